// Round 5
// baseline (326.512 us; speedup 1.0000x reference)
//
#include <hip/hip_runtime.h>

// H=16, DK=DV=64, D=1024, N=M=2048.
// scores[h,n,m] = ((A_h^T q_n + vh_h) . k_m)/8 + row-consts (drop in softmax),
//   A_h[i][j] = sum_d Wq[h,i,d]*Wk[h,j,d],  vh_h[j] = sum_d Wk[h,j,d]*bq[h,d].
// out[dp] = sum_{h,v} r[h,v]*G[h*64+v][dp] + cvec[dp],
//   G = Wv2 @ Wo^T (Wv2[(h*64+v)][d] = Wv[h,v,d]),
//   cvec[dp] = (2048*sum_h bv[h,:]) . Wo[dp,:] + bo[dp],
//   r_h[v] = sum_n softmax_row . V[:,v].
// No max-tracking softmax: |s|max ~ 27 << 88 -> exp(s) safe in fp32.
// R5: 2 launches total. Flash main loop has ZERO barriers (K,V frags direct
// from global bf16; P wave-private LDS); out-projection fused via G + atomics.

typedef __attribute__((ext_vector_type(4))) float floatx4;
typedef __attribute__((ext_vector_type(8))) short shortx8;

#define MFMA(a, b, c) __builtin_amdgcn_mfma_f32_16x16x32_bf16(a, b, c, 0, 0, 0)

__device__ inline unsigned short f2bf(float f) {
    unsigned int u = __float_as_uint(f);
    u += 0x7FFFu + ((u >> 16) & 1u);   // RNE
    return (unsigned short)(u >> 16);
}
__device__ inline float bf2f(unsigned short s) {
    return __uint_as_float(((unsigned int)s) << 16);
}

// =================== prep: 320 independent blocks ============================
// bx 0..15  : per-head At (bf16 A^T) + vh (fp32) via MFMA
// bx 16..31 : Kb = bf16(keys) row-major
// bx 32..63 : VT = bf16(values)^T
// bx 64..319: G = Wv2 @ Wo^T (fp32 out, bf16 MFMA); ib==0 also writes
//             out[dp] = cvec[dp] (initializes d_out for flash atomics)
__global__ __launch_bounds__(256) void prep_kernel(
    const float* __restrict__ Wq, const float* __restrict__ Wk,
    const float* __restrict__ bq, const float* __restrict__ keys,
    const float* __restrict__ values, const float* __restrict__ Wv,
    const float* __restrict__ bv, const float* __restrict__ Wo,
    const float* __restrict__ bo,
    unsigned short* __restrict__ At, float* __restrict__ vh,
    unsigned short* __restrict__ Kb, unsigned short* __restrict__ VT,
    float* __restrict__ G, float* __restrict__ out) {
    const int tid = threadIdx.x;
    const int bx = blockIdx.x;
    const int w = tid >> 6, lane = tid & 63;
    const int ln = lane & 15, quad = lane >> 4;
    __shared__ __align__(16) unsigned char sm[19968];

    if (bx < 16) {
        const int h = bx;
        unsigned short* Qs = (unsigned short*)sm;            // 64x72
        unsigned short* Ks = (unsigned short*)(sm + 9216);   // 64x72
        float* bqs = (float*)(sm + 18432);                   // 64
        float* vred = (float*)(sm + 18688);                  // 4x64
        const int row = tid >> 2, seg = (tid & 3) * 16;
        const int j = tid & 63, half = tid >> 6;
        floatx4 accA[4] = {};
        float vacc = 0.f;
        for (int c = 0; c < 16; ++c) {
            const int k0 = c * 64;
            const float* wqp = Wq + (size_t)(h * 64 + row) * 1024 + k0 + seg;
            const float* wkp = Wk + (size_t)(h * 64 + row) * 1024 + k0 + seg;
            #pragma unroll
            for (int u = 0; u < 4; ++u) {
                float4 a = *(const float4*)&wqp[u * 4];
                float4 b = *(const float4*)&wkp[u * 4];
                *(ushort4*)&Qs[row * 72 + seg + u * 4] =
                    (ushort4){f2bf(a.x), f2bf(a.y), f2bf(a.z), f2bf(a.w)};
                *(ushort4*)&Ks[row * 72 + seg + u * 4] =
                    (ushort4){f2bf(b.x), f2bf(b.y), f2bf(b.z), f2bf(b.w)};
            }
            if (tid < 64) bqs[tid] = bq[h * 1024 + k0 + tid];
            __syncthreads();
            #pragma unroll
            for (int u = 0; u < 16; ++u)
                vacc += bf2f(Ks[j * 72 + half * 16 + u]) * bqs[half * 16 + u];
            shortx8 a0 = *(shortx8*)&Qs[(w * 16 + ln) * 72 + quad * 8];
            shortx8 a1 = *(shortx8*)&Qs[(w * 16 + ln) * 72 + 32 + quad * 8];
            #pragma unroll
            for (int cn = 0; cn < 4; ++cn) {
                shortx8 b0 = *(shortx8*)&Ks[(cn * 16 + ln) * 72 + quad * 8];
                shortx8 b1 = *(shortx8*)&Ks[(cn * 16 + ln) * 72 + 32 + quad * 8];
                accA[cn] = MFMA(a0, b0, accA[cn]);
                accA[cn] = MFMA(a1, b1, accA[cn]);
            }
            __syncthreads();
        }
        #pragma unroll
        for (int cn = 0; cn < 4; ++cn)
            #pragma unroll
            for (int r = 0; r < 4; ++r)
                At[h * 4096 + (cn * 16 + ln) * 64 + w * 16 + quad * 4 + r] =
                    f2bf(accA[cn][r]);
        vred[half * 64 + j] = vacc;
        __syncthreads();
        if (tid < 64)
            vh[h * 64 + tid] = vred[tid] + vred[64 + tid] +
                               vred[128 + tid] + vred[192 + tid];
    } else if (bx < 32) {
        const int bk = bx - 16;
        const int base = (bk * 256 + tid) * 32;
        #pragma unroll
        for (int u = 0; u < 8; ++u) {
            float4 a = *(const float4*)&keys[base + u * 4];
            *(ushort4*)&Kb[base + u * 4] =
                (ushort4){f2bf(a.x), f2bf(a.y), f2bf(a.z), f2bf(a.w)};
        }
    } else if (bx < 64) {
        const int m0 = (bx - 32) * 64;
        unsigned short* vts = (unsigned short*)sm;   // 64x72
        #pragma unroll
        for (int it = 0; it < 4; ++it) {
            int gi = tid + it * 256;
            int m = gi >> 4, c4 = (gi & 15) * 4;
            float4 a = *(const float4*)&values[(size_t)(m0 + m) * 64 + c4];
            vts[(c4 + 0) * 72 + m] = f2bf(a.x);
            vts[(c4 + 1) * 72 + m] = f2bf(a.y);
            vts[(c4 + 2) * 72 + m] = f2bf(a.z);
            vts[(c4 + 3) * 72 + m] = f2bf(a.w);
        }
        __syncthreads();
        #pragma unroll
        for (int it = 0; it < 2; ++it) {
            int gi = tid + it * 256;
            int v = gi >> 3, sg = (gi & 7) * 8;
            *(shortx8*)&VT[v * 2048 + m0 + sg] = *(shortx8*)&vts[v * 72 + sg];
        }
    } else {
        const int idx = bx - 64, ib = idx >> 4, jb = idx & 15;
        unsigned short* As = (unsigned short*)sm;            // 64x72 (hv rows)
        unsigned short* Bs = (unsigned short*)(sm + 9216);   // 64x72 (dp rows)
        float* cbuf = (float*)(sm + 18432);                  // 64
        const int row = tid >> 2, seg = (tid & 3) * 16;
        floatx4 accG[4] = {};
        float cacc = 0.f;
        for (int c = 0; c < 16; ++c) {
            const int k0 = c * 64;
            const float* ap = Wv + (size_t)(ib * 64 + row) * 1024 + k0 + seg;
            const float* bp = Wo + (size_t)(jb * 64 + row) * 1024 + k0 + seg;
            #pragma unroll
            for (int u = 0; u < 4; ++u) {
                float4 a = *(const float4*)&ap[u * 4];
                float4 b = *(const float4*)&bp[u * 4];
                *(ushort4*)&As[row * 72 + seg + u * 4] =
                    (ushort4){f2bf(a.x), f2bf(a.y), f2bf(a.z), f2bf(a.w)};
                *(ushort4*)&Bs[row * 72 + seg + u * 4] =
                    (ushort4){f2bf(b.x), f2bf(b.y), f2bf(b.z), f2bf(b.w)};
            }
            if (ib == 0 && tid < 64) {
                float ssum = 0.f;
                #pragma unroll
                for (int hh = 0; hh < 16; ++hh) ssum += bv[hh * 1024 + k0 + tid];
                cbuf[tid] = 2048.0f * ssum;
            }
            __syncthreads();
            shortx8 a0 = *(shortx8*)&As[(w * 16 + ln) * 72 + quad * 8];
            shortx8 a1 = *(shortx8*)&As[(w * 16 + ln) * 72 + 32 + quad * 8];
            #pragma unroll
            for (int cn = 0; cn < 4; ++cn) {
                shortx8 b0 = *(shortx8*)&Bs[(cn * 16 + ln) * 72 + quad * 8];
                shortx8 b1 = *(shortx8*)&Bs[(cn * 16 + ln) * 72 + 32 + quad * 8];
                accG[cn] = MFMA(a0, b0, accG[cn]);
                accG[cn] = MFMA(a1, b1, accG[cn]);
            }
            if (ib == 0 && tid < 64) {
                #pragma unroll
                for (int dd = 0; dd < 64; ++dd)
                    cacc += bf2f(Bs[tid * 72 + dd]) * cbuf[dd];
            }
            __syncthreads();
        }
        #pragma unroll
        for (int cn = 0; cn < 4; ++cn)
            #pragma unroll
            for (int r = 0; r < 4; ++r)
                G[(size_t)(ib * 64 + w * 16 + quad * 4 + r) * 1024 +
                  jb * 64 + cn * 16 + ln] = accG[cn][r];
        if (ib == 0 && tid < 64)
            out[jb * 64 + tid] = cacc + bo[jb * 64 + tid];
    }
}

// =================== flash: grid (64 qtiles of 32 rows, 16 heads) ============
// 4 waves: wave w -> rows (w&1)*16..+15, key chunk (w>>1)*1024 (16 steps).
// Main loop barrier-free: K/V frags from global bf16, P wave-private LDS.
// Epilogue: partial r -> atomicAdd contributions to out via G.
__global__ __launch_bounds__(256, 4) void flash_kernel(
    const float* __restrict__ queries, const unsigned short* __restrict__ At,
    const float* __restrict__ vh, const unsigned short* __restrict__ Kb,
    const unsigned short* __restrict__ VT, const float* __restrict__ G,
    float* __restrict__ out) {
    const int h = blockIdx.y;
    const int n0 = blockIdx.x * 32;
    const int tid = threadIdx.x;
    const int w = tid >> 6, lane = tid & 63;
    const int ln = lane & 15, quad = lane >> 4;
    const int cw = w >> 1;    // key chunk
    const int rw = w & 1;     // row half

    __shared__ __align__(16) unsigned char lds[19456];
    unsigned short* Pw = (unsigned short*)(lds + w * 2304);   // 16x72 / wave
    unsigned short* qh = (unsigned short*)(lds + 9216);       // 32x72
    unsigned short* qstage = (unsigned short*)(lds + 13824);  // 32x72
    float* vhs = (float*)(lds + 18432);                       // 64

    // stage queries (32 rows, bf16)
    {
        int row = tid >> 3, sg = (tid & 7) * 8;
        const float* qp = queries + (size_t)(n0 + row) * 64 + sg;
        float4 a = *(const float4*)&qp[0];
        float4 b = *(const float4*)&qp[4];
        *(ushort4*)&qstage[row * 72 + sg] =
            (ushort4){f2bf(a.x), f2bf(a.y), f2bf(a.z), f2bf(a.w)};
        *(ushort4*)&qstage[row * 72 + sg + 4] =
            (ushort4){f2bf(b.x), f2bf(b.y), f2bf(b.z), f2bf(b.w)};
    }
    if (tid < 64) vhs[tid] = vh[h * 64 + tid];
    __syncthreads();
    // qhat = (q.A + vh)*0.125 ; waves 0,1 compute 16 rows each (B=At global)
    if (w < 2) {
        const unsigned short* Ah = At + h * 4096;
        shortx8 qa0 = *(shortx8*)&qstage[(w * 16 + ln) * 72 + quad * 8];
        shortx8 qa1 = *(shortx8*)&qstage[(w * 16 + ln) * 72 + 32 + quad * 8];
        #pragma unroll
        for (int cn = 0; cn < 4; ++cn) {
            floatx4 acc = {};
            shortx8 b0 = *(const shortx8*)&Ah[(cn * 16 + ln) * 64 + quad * 8];
            shortx8 b1 = *(const shortx8*)&Ah[(cn * 16 + ln) * 64 + 32 + quad * 8];
            acc = MFMA(qa0, b0, acc);
            acc = MFMA(qa1, b1, acc);
            #pragma unroll
            for (int r = 0; r < 4; ++r)
                qh[(w * 16 + quad * 4 + r) * 72 + cn * 16 + ln] =
                    f2bf((acc[r] + vhs[cn * 16 + ln]) * 0.125f);
        }
    }
    __syncthreads();
    shortx8 qf0 = *(shortx8*)&qh[(rw * 16 + ln) * 72 + quad * 8];
    shortx8 qf1 = *(shortx8*)&qh[(rw * 16 + ln) * 72 + 32 + quad * 8];

    // ---- barrier-free main loop ----
    floatx4 O[4] = {};
    float lacc[4] = {0.f, 0.f, 0.f, 0.f};
    shortx8 kf[8], vf[8];
    #pragma unroll
    for (int cm = 0; cm < 4; ++cm) {
        const unsigned short* kp = Kb + (size_t)(cw * 1024 + cm * 16 + ln) * 64;
        kf[cm * 2 + 0] = *(const shortx8*)&kp[quad * 8];
        kf[cm * 2 + 1] = *(const shortx8*)&kp[32 + quad * 8];
        const unsigned short* vp = VT + (cm * 16 + ln) * 2048 + cw * 1024;
        vf[cm * 2 + 0] = *(const shortx8*)&vp[quad * 8];
        vf[cm * 2 + 1] = *(const shortx8*)&vp[32 + quad * 8];
    }
    for (int s = 0; s < 16; ++s) {
        floatx4 S[4];
        #pragma unroll
        for (int cm = 0; cm < 4; ++cm) {
            floatx4 a = {};
            a = MFMA(qf0, kf[cm * 2], a);
            a = MFMA(qf1, kf[cm * 2 + 1], a);
            S[cm] = a;
        }
        const int sn = (s < 15) ? s + 1 : 15;
        #pragma unroll
        for (int cm = 0; cm < 4; ++cm) {   // prefetch K(s+1) into same regs
            const unsigned short* kp =
                Kb + (size_t)(cw * 1024 + sn * 64 + cm * 16 + ln) * 64;
            kf[cm * 2 + 0] = *(const shortx8*)&kp[quad * 8];
            kf[cm * 2 + 1] = *(const shortx8*)&kp[32 + quad * 8];
        }
        #pragma unroll
        for (int cm = 0; cm < 4; ++cm) {
            #pragma unroll
            for (int r = 0; r < 4; ++r) {
                float p = __expf(S[cm][r]);
                lacc[r] += p;
                Pw[(quad * 4 + r) * 72 + cm * 16 + ln] = f2bf(p);
            }
        }
        shortx8 pf0 = *(shortx8*)&Pw[ln * 72 + quad * 8];
        shortx8 pf1 = *(shortx8*)&Pw[ln * 72 + 32 + quad * 8];
        #pragma unroll
        for (int cv = 0; cv < 4; ++cv) {
            O[cv] = MFMA(pf0, vf[cv * 2], O[cv]);
            O[cv] = MFMA(pf1, vf[cv * 2 + 1], O[cv]);
        }
        #pragma unroll
        for (int cv = 0; cv < 4; ++cv) {   // prefetch V(s+1)
            const unsigned short* vp =
                VT + (cv * 16 + ln) * 2048 + cw * 1024 + sn * 64;
            vf[cv * 2 + 0] = *(const shortx8*)&vp[quad * 8];
            vf[cv * 2 + 1] = *(const shortx8*)&vp[32 + quad * 8];
        }
    }

    // ---- epilogue: combine chunk partials, normalize, project via G ----
    float lred[4];
    #pragma unroll
    for (int r = 0; r < 4; ++r) {
        float x = lacc[r];
        #pragma unroll
        for (int o = 1; o <= 8; o <<= 1) x += __shfl_xor(x, o);
        lred[r] = x;
    }
    __syncthreads();   // all waves done with Pw/qh regions
    float* Obuf = (float*)lds;               // [64][68]
    float* LSUM = (float*)(lds + 17408);     // [64]
    float* red  = (float*)(lds + 17664);     // [4][64]
    float* pr   = (float*)(lds + 18688);     // [64]
    #pragma unroll
    for (int cv = 0; cv < 4; ++cv)
        #pragma unroll
        for (int r = 0; r < 4; ++r)
            Obuf[(w * 16 + quad * 4 + r) * 68 + cv * 16 + ln] = O[cv][r];
    if (ln == 0) {
        #pragma unroll
        for (int r = 0; r < 4; ++r) LSUM[w * 16 + quad * 4 + r] = lred[r];
    }
    __syncthreads();
    {
        int v = tid & 63, grp = tid >> 6;
        float acc = 0.f;
        #pragma unroll
        for (int u = 0; u < 8; ++u) {
            int row = grp * 8 + u;                        // 0..31
            int sA = (row >> 4) * 16 + (row & 15);        // chunk-0 slot
            int sB = sA + 32;                             // chunk-1 slot
            acc += (Obuf[sA * 68 + v] + Obuf[sB * 68 + v]) /
                   (LSUM[sA] + LSUM[sB]);
        }
        red[grp * 64 + v] = acc;
    }
    __syncthreads();
    if (tid < 64)
        pr[tid] = red[tid] + red[64 + tid] + red[128 + tid] + red[192 + tid];
    __syncthreads();
    {
        const float* Gh = G + (size_t)(h * 64) * 1024 + tid * 4;
        float ax = 0.f, ay = 0.f, az = 0.f, aw = 0.f;
        #pragma unroll 8
        for (int v = 0; v < 64; ++v) {
            float4 g = *(const float4*)&Gh[(size_t)v * 1024];
            float pv = pr[v];
            ax += pv * g.x; ay += pv * g.y; az += pv * g.z; aw += pv * g.w;
        }
        atomicAdd(&out[tid * 4 + 0], ax);
        atomicAdd(&out[tid * 4 + 1], ay);
        atomicAdd(&out[tid * 4 + 2], az);
        atomicAdd(&out[tid * 4 + 3], aw);
    }
}

extern "C" void kernel_launch(void* const* d_in, const int* in_sizes, int n_in,
                              void* d_out, int out_size, void* d_ws, size_t ws_size,
                              hipStream_t stream) {
    const float* queries = (const float*)d_in[0];
    const float* keys    = (const float*)d_in[1];
    const float* values  = (const float*)d_in[2];
    const float* Wq      = (const float*)d_in[3];
    const float* bq      = (const float*)d_in[4];
    const float* Wk      = (const float*)d_in[5];
    // d_in[6] = bk: row-constant under softmax, unused
    const float* Wv      = (const float*)d_in[7];
    const float* bv      = (const float*)d_in[8];
    const float* Wo      = (const float*)d_in[9];
    const float* bo      = (const float*)d_in[10];
    float* out = (float*)d_out;

    unsigned short* At = (unsigned short*)d_ws;          // 16*4096 us (128 KB)
    float* vh = (float*)(At + 65536);                    // 1024 f (4 KB)
    unsigned short* Kb = (unsigned short*)(vh + 1024);   // 2048*64 us (256 KB)
    unsigned short* VT = Kb + 131072;                    // 64*2048 us (256 KB)
    float* G = (float*)(VT + 131072);                    // 1024*1024 f (4 MB)
    // total ws: ~4.64 MB

    prep_kernel<<<320, 256, 0, stream>>>(Wq, Wk, bq, keys, values, Wv, bv,
                                         Wo, bo, At, vh, Kb, VT, G, out);
    flash_kernel<<<dim3(64, 16), 256, 0, stream>>>(queries, At, vh, Kb, VT,
                                                   G, out);
}